// Round 1
// baseline (1226.268 us; speedup 1.0000x reference)
//
#include <hip/hip_runtime.h>

// Masked split-context/center 3x3 conv, implicit GEMM, bf16 MFMA 16x16x32.
// M = 8*256*256 (b,h,w), N = 256 f, K = 9 taps * 128 ch (ctx tap4 masked -> center).
//
// V2 structure:
//  - A (x rows) staged per dy-slab ONCE into LDS (130 w x 128 ch, halo'd),
//    all 3 dx taps read shifted views of the same slab. 4th slab = center chans.
//  - B (weights) pre-packed ONCE by prep kernel into fragment-major bf16 in d_ws:
//    Bp[tapg][kb][fg][lane][8] -> each wave B-fragment is one coalesced 1KB load
//    from L2 (2.4MB total, fully cached). No LDS for B, no per-block transpose.
//  - 8 barriers/block (2 per slab) instead of 72.
//  - Bijective XCD swizzle (8192%8==0) so h-neighbor blocks share an L2.
//  - Non-temporal C stores to keep streaming writes from evicting x rows in L2.

typedef __attribute__((ext_vector_type(8))) short bf16x8;   // 8 bf16 = 4 VGPRs
typedef __attribute__((ext_vector_type(4))) float f32x4;

#define PC 136        // Asl row stride in elements: 272B, 16B-aligned, bank step 4
#define NTAPG 10      // 9 ctx tap slots (slot 4 zeroed/masked) + 1 center

__device__ __forceinline__ short f2bf(float f) {
  // round-to-nearest-even fp32 -> bf16 (inputs are finite normals)
  union { float f; unsigned u; } a; a.f = f;
  unsigned r = a.u + 0x7FFFu + ((a.u >> 16) & 1u);
  return (short)(r >> 16);
}

// ---- prep: kern fp32 (3,3,2,128,256) -> fragment-major bf16 ----
// Bp element index: (((tapg*4 + kb)*16 + fg)*64 + lane)*8 + ke
//   f = fg*16 + (lane&15), k = kb*32 + (lane>>4)*8 + ke
__global__ __launch_bounds__(256) void prep_w(const float* __restrict__ kern,
                                              short* __restrict__ Bp) {
  const int idx = blockIdx.x * 256 + threadIdx.x;   // 40960 fragments-of-8
  const int fl = idx & 15, kq = (idx >> 4) & 3, fg = (idx >> 6) & 15,
            kb = (idx >> 10) & 3, tapg = idx >> 12;
  if (tapg >= NTAPG) return;
  const int f  = fg * 16 + fl;
  const int k0 = kb * 32 + kq * 8;
  const int gidx = (tapg < 9) ? tapg * 2 : 9;       // (tap*2 + g) plane
  union { short s[8]; uint4 u; } o;
#pragma unroll
  for (int e = 0; e < 8; ++e) {
    float v = (tapg == 4) ? 0.f                     // masked ctx center tap
            : kern[(size_t)(gidx * 128 + k0 + e) * 256 + f];
    o.s[e] = f2bf(v);
  }
  *(uint4*)&Bp[(size_t)idx * 8] = o.u;
}

__global__ __launch_bounds__(256, 2) void scc_conv(
    const float* __restrict__ x, const short* __restrict__ Bp,
    const float* __restrict__ bias, float* __restrict__ out)
{
  __shared__ short Asl[130 * PC];   // one dy-slab: [w-halo 130][128 ch padded]

  const int tid = threadIdx.x;

  // bijective XCD swizzle: grid 8192 = 8 XCDs * 1024
  const int bid = (int)blockIdx.x;
  const int wg  = (bid & 7) * 1024 + (bid >> 3);
  const int bn  = wg & 1;               // f half
  const int bm  = wg >> 1;              // m tile
  const int m0  = bm * 128;
  const int b   = m0 >> 16;
  const int h   = (m0 >> 8) & 255;
  const int w0  = m0 & 255;             // 0 or 128

  const int lane = tid & 63;
  const int wid  = tid >> 6;
  const int wm   = wid >> 1;
  const int wn   = wid & 1;
  const int fl   = lane & 15;
  const int kq   = lane >> 4;

  const int s_row0 = tid >> 5;          // 8 rows staged per pass
  const int s_c4   = (tid & 31) * 4;    // 32 thr * float4 = full 128-ch row

  f32x4 acc[4][4];
#pragma unroll
  for (int i = 0; i < 4; ++i)
#pragma unroll
    for (int j = 0; j < 4; ++j) acc[i][j] = (f32x4){0.f, 0.f, 0.f, 0.f};

  const float* __restrict__ xb = x + (size_t)b * (256 * 256 * 256);

#pragma unroll 1
  for (int slab = 0; slab < 4; ++slab) {
    // slab 0..2: ctx channels, row h+slab-1 ; slab 3: center channels, row h
    const int  hh    = (slab < 3) ? (h + slab - 1) : h;
    const bool hok   = ((unsigned)hh) < 256u;
    const int  cbase = (slab < 3) ? 0 : 128;

    __syncthreads();                    // prior slab's fragment reads done
#pragma unroll 4
    for (int s = s_row0; s < 130; s += 8) {
      const int w = w0 - 1 + s;
      float4 v = make_float4(0.f, 0.f, 0.f, 0.f);
      if (hok && (unsigned)w < 256u)
        v = *(const float4*)(xb + ((size_t)hh * 256 + w) * 256 + cbase + s_c4);
      union { short s[4]; uint2 u; } p;
      p.s[0] = f2bf(v.x); p.s[1] = f2bf(v.y);
      p.s[2] = f2bf(v.z); p.s[3] = f2bf(v.w);
      *(uint2*)&Asl[s * PC + s_c4] = p.u;
    }
    __syncthreads();                    // slab visible

    const int ndx = (slab < 3) ? 3 : 1;
#pragma unroll 1
    for (int dx = 0; dx < ndx; ++dx) {
      int tapg, sofs;
      if (slab < 3) {
        if (slab == 1 && dx == 1) continue;   // masked ctx tap (center pos)
        tapg = slab * 3 + dx; sofs = dx;      // slab idx s = mlocal + dx
      } else { tapg = 9; sofs = 1; }

      // per-lane base into fragment-major weights; each read = 1KB/wave coalesced
      const short* __restrict__ bpt =
          Bp + (((size_t)tapg * 64 + bn * 8 + wn * 4) * 64 + lane) * 8;

#pragma unroll
      for (int kb = 0; kb < 4; ++kb) {
        bf16x8 af[4], bfr[4];
#pragma unroll
        for (int j = 0; j < 4; ++j)
          bfr[j] = *(const bf16x8*)(bpt + (size_t)(kb * 16 + j) * 512);
#pragma unroll
        for (int i = 0; i < 4; ++i)
          af[i] = *(const bf16x8*)
              &Asl[(wm * 64 + i * 16 + fl + sofs) * PC + kb * 32 + kq * 8];
#pragma unroll
        for (int i = 0; i < 4; ++i)
#pragma unroll
          for (int j = 0; j < 4; ++j)
            acc[i][j] = __builtin_amdgcn_mfma_f32_16x16x32_bf16(
                af[i], bfr[j], acc[i][j], 0, 0, 0);
      }
    }
  }

  // ---- epilogue: C row = kq*4+r, col = fl per 16x16 tile; nt streaming stores ----
  const int of0 = bn * 128 + wn * 64;
  float bvals[4];
#pragma unroll
  for (int j = 0; j < 4; ++j) bvals[j] = bias[of0 + j * 16 + fl];

#pragma unroll
  for (int i = 0; i < 4; ++i) {
    const int mrow = m0 + wm * 64 + i * 16 + kq * 4;
#pragma unroll
    for (int j = 0; j < 4; ++j) {
      const int f = of0 + j * 16 + fl;
#pragma unroll
      for (int r = 0; r < 4; ++r)
        __builtin_nontemporal_store(acc[i][j][r] + bvals[j],
                                    &out[(size_t)(mrow + r) * 256 + f]);
    }
  }
}

extern "C" void kernel_launch(void* const* d_in, const int* in_sizes, int n_in,
                              void* d_out, int out_size, void* d_ws, size_t ws_size,
                              hipStream_t stream) {
  const float* x    = (const float*)d_in[0];
  const float* kern = (const float*)d_in[1];
  const float* bias = (const float*)d_in[2];
  float* out = (float*)d_out;
  short* Bp  = (short*)d_ws;           // needs 10*4096*8*2 = 655,360 B

  prep_w<<<dim3(160), dim3(256), 0, stream>>>(kern, Bp);
  scc_conv<<<dim3(8192), dim3(256), 0, stream>>>(x, Bp, bias, out);
}